// Round 14
// baseline (755.638 us; speedup 1.0000x reference)
//
#include <hip/hip_runtime.h>

#define DIM 64
#define BSH 8           // bucket shift: 256 rows per bucket
#define BROWS 256
#define MAXNB 1023      // max buckets (single-tile scans use 1024 threads)
#define EPB 4096        // edges per chunk (32KB LDS staging)
#define MAXNBLK 2048    // max chunks (ne <= 8.38M)

// ---------------- utility ----------------
__global__ void zero_f4(float* __restrict__ p, size_t n4) {
    size_t i = (size_t)blockIdx.x * blockDim.x + threadIdx.x;
    size_t stride = (size_t)gridDim.x * blockDim.x;
    float4 z = make_float4(0.f, 0.f, 0.f, 0.f);
    for (; i < n4; i += stride)
        reinterpret_cast<float4*>(p)[i] = z;
}

__device__ __forceinline__ unsigned int bf16_rne(float f) {
    unsigned int u = __float_as_uint(f);
    return (u + 0x7FFFu + ((u >> 16) & 1u)) >> 16;
}

// float -> bf16 (RNE), 4 elems/thread, grid-stride
__global__ void f32_to_bf16(const float* __restrict__ src,
                            unsigned short* __restrict__ dst, int n4) {
    int i = blockIdx.x * blockDim.x + threadIdx.x;
    int stride = gridDim.x * blockDim.x;
    for (; i < n4; i += stride) {
        float4 v = *reinterpret_cast<const float4*>(src + (size_t)i * 4);
        ushort4 o;
        o.x = (unsigned short)bf16_rne(v.x);
        o.y = (unsigned short)bf16_rne(v.y);
        o.z = (unsigned short)bf16_rne(v.z);
        o.w = (unsigned short)bf16_rne(v.w);
        *reinterpret_cast<ushort4*>(dst + (size_t)i * 4) = o;
    }
}

// ---------------- pass 1: per-chunk bucket histogram (vectorized reads) ----------------
__global__ __launch_bounds__(1024) void count_chunks(const int* __restrict__ row,
                                                     int* __restrict__ runcnt,
                                                     int ne, int nb) {
    __shared__ int h[1024];
    int blk = blockIdx.x, t = threadIdx.x;
    h[t] = 0;
    __syncthreads();
    int base = blk * EPB;
    int lim = base + EPB; if (lim > ne) lim = ne;
    if (lim - base == EPB) {
        int4 r4 = *reinterpret_cast<const int4*>(row + base + t * 4);
        atomicAdd(&h[r4.x >> BSH], 1);
        atomicAdd(&h[r4.y >> BSH], 1);
        atomicAdd(&h[r4.z >> BSH], 1);
        atomicAdd(&h[r4.w >> BSH], 1);
    } else {
        for (int e = base + t; e < lim; e += 1024)
            atomicAdd(&h[row[e] >> BSH], 1);
    }
    __syncthreads();
    if (t < nb) runcnt[(size_t)blk * nb + t] = h[t];
}

// ---------------- pass 2a: per-bucket exclusive scan across chunks (in place) ----------------
__global__ __launch_bounds__(1024) void scan_chunks(int* __restrict__ runcnt,
                                                    int* __restrict__ btotal,
                                                    int nb, int nblk) {
    __shared__ int sc[1024];
    __shared__ int carry;
    int b = blockIdx.x, t = threadIdx.x;
    if (t == 0) carry = 0;
    __syncthreads();
    for (int off = 0; off < nblk; off += 1024) {
        int i = off + t;
        int v = (i < nblk) ? runcnt[(size_t)i * nb + b] : 0;
        sc[t] = v;
        __syncthreads();
        for (int d = 1; d < 1024; d <<= 1) {
            int a = (t >= d) ? sc[t - d] : 0;
            __syncthreads();
            sc[t] += a;
            __syncthreads();
        }
        int excl = carry + sc[t] - v;
        if (i < nblk) runcnt[(size_t)i * nb + b] = excl;
        __syncthreads();
        if (t == 1023) carry += sc[1023];
        __syncthreads();
    }
    if (t == 0) btotal[b] = carry;
}

// ---------------- pass 2b: exclusive scan of bucket totals -> bstart ----------------
__global__ __launch_bounds__(1024) void scan_buckets(const int* __restrict__ btotal,
                                                     int* __restrict__ bstart, int nb) {
    __shared__ int sc[1024];
    int t = threadIdx.x;
    int v = (t < nb) ? btotal[t] : 0;
    sc[t] = v;
    __syncthreads();
    for (int d = 1; d < 1024; d <<= 1) {
        int a = (t >= d) ? sc[t - d] : 0;
        __syncthreads();
        sc[t] += a;
        __syncthreads();
    }
    if (t < nb) bstart[t] = sc[t] - v;
    if (t == 0) bstart[nb] = sc[1023];
}

// ---------------- pass 3: LDS-staged scatter with coalesced writeout ----------------
// Sorts the chunk by bucket in LDS, then writes each bucket-run with consecutive
// lanes -> consecutive addresses. packs {col | row_lo<<18, val}.
__global__ __launch_bounds__(1024) void scatter3(const int* __restrict__ row,
                                                 const int* __restrict__ col,
                                                 const float* __restrict__ val,
                                                 const int* __restrict__ bstart,
                                                 const int* __restrict__ runcnt,
                                                 int2* __restrict__ ebuf,
                                                 int ne, int nb) {
    __shared__ int2 data[EPB];            // 32 KB
    __shared__ unsigned short bkt[EPB];   // 8 KB
    __shared__ int cur[1024];             // hist -> local cursor
    __shared__ int gbase[1024];
    __shared__ int sc[1024];
    int blk = blockIdx.x, t = threadIdx.x;
    int base = blk * EPB;
    int lim = base + EPB; if (lim > ne) lim = ne;
    int len = lim - base;
    bool full = (len == EPB);

    cur[t] = 0;
    __syncthreads();
    if (full) {
        int4 r4 = *reinterpret_cast<const int4*>(row + base + t * 4);
        atomicAdd(&cur[r4.x >> BSH], 1);
        atomicAdd(&cur[r4.y >> BSH], 1);
        atomicAdd(&cur[r4.z >> BSH], 1);
        atomicAdd(&cur[r4.w >> BSH], 1);
    } else {
        for (int e = base + t; e < lim; e += 1024)
            atomicAdd(&cur[row[e] >> BSH], 1);
    }
    __syncthreads();

    int v = cur[t];
    sc[t] = v;
    __syncthreads();
    for (int d = 1; d < 1024; d <<= 1) {
        int a = (t >= d) ? sc[t - d] : 0;
        __syncthreads();
        sc[t] += a;
        __syncthreads();
    }
    int excl = sc[t] - v;
    if (t < nb) gbase[t] = bstart[t] + runcnt[(size_t)blk * nb + t] - excl;
    cur[t] = excl;
    __syncthreads();

    if (full) {
        int4   r4 = *reinterpret_cast<const int4*>(row + base + t * 4);
        int4   c4 = *reinterpret_cast<const int4*>(col + base + t * 4);
        float4 v4 = *reinterpret_cast<const float4*>(val + base + t * 4);
        int rr[4] = {r4.x, r4.y, r4.z, r4.w};
        int cc[4] = {c4.x, c4.y, c4.z, c4.w};
        float vv[4] = {v4.x, v4.y, v4.z, v4.w};
        #pragma unroll
        for (int k = 0; k < 4; ++k) {
            int b = rr[k] >> BSH;
            int pos = atomicAdd(&cur[b], 1);
            data[pos] = make_int2(cc[k] | ((rr[k] & (BROWS - 1)) << 18),
                                  __float_as_int(vv[k]));
            bkt[pos] = (unsigned short)b;
        }
    } else {
        for (int e = base + t; e < lim; e += 1024) {
            int r = row[e];
            int b = r >> BSH;
            int pos = atomicAdd(&cur[b], 1);
            data[pos] = make_int2(col[e] | ((r & (BROWS - 1)) << 18), __float_as_int(val[e]));
            bkt[pos] = (unsigned short)b;
        }
    }
    __syncthreads();

    for (int i = t; i < len; i += 1024) {
        int b = bkt[i];
        ebuf[gbase[b] + i] = data[i];
    }
}

// ---------------- pass 4: block per 256-row bucket, 256-bin row sort ----------------
__global__ __launch_bounds__(512) void local_sort(const int2* __restrict__ ein,
                                                  const int* __restrict__ bstart,
                                                  int2* __restrict__ eout,
                                                  int* __restrict__ rowptr,
                                                  int nrows, int nb) {
    __shared__ int hist[BROWS];
    __shared__ int cur[BROWS];
    __shared__ int wsum[4];
    int b = blockIdx.x;
    int t = threadIdx.x;
    int beg = bstart[b], end = bstart[b + 1];
    if (t < BROWS) hist[t] = 0;
    __syncthreads();
    for (int e = beg + t; e < end; e += 512)
        atomicAdd(&hist[((unsigned)ein[e].x) >> 18], 1);
    __syncthreads();
    int v = 0, s = 0;
    if (t < BROWS) {
        v = hist[t];
        s = v;
        #pragma unroll
        for (int off = 1; off < 64; off <<= 1) {
            int a = __shfl_up(s, off);
            if ((t & 63) >= off) s += a;
        }
        if ((t & 63) == 63) wsum[t >> 6] = s;
    }
    __syncthreads();
    if (t < BROWS) {
        int woff = 0;
        #pragma unroll
        for (int w = 0; w < 4; ++w)
            if (w < (t >> 6)) woff += wsum[w];
        int excl = woff + s - v;
        cur[t] = excl;
        int r = (b << BSH) + t;
        if (r < nrows) rowptr[r] = beg + excl;
    }
    if (b == nb - 1 && t == 0) rowptr[nrows] = end;
    __syncthreads();
    for (int e = beg + t; e < end; e += 512) {
        int2 cv = ein[e];
        int rl = ((unsigned)cv.x) >> 18;
        int pos = beg + atomicAdd(&cur[rl], 1);
        eout[pos] = make_int2(cv.x & 0x3FFFF, cv.y);
    }
}

// ---------------- bf16 CSR SpMM: one wave per row, 8 edges x 8 lanes x 16B ----------------
// Gathers bf16 rows (128 B), accumulates fp32, writes bf16 (OUT16) or fp32 (!OUT16).
// Plain int2 edge load — NT variants measured slower twice. unroll 8 for 16 loads in flight.
template<bool OUT16>
__global__ __launch_bounds__(256) void spmm_bf16(const int2* __restrict__ colval,
                                                 const int* __restrict__ rowptr,
                                                 const unsigned short* __restrict__ xb,
                                                 float* __restrict__ yf,
                                                 unsigned short* __restrict__ yb,
                                                 int nrows) {
    int wid  = (int)(((size_t)blockIdx.x * blockDim.x + threadIdx.x) >> 6);
    int lane = threadIdx.x & 63;
    if (wid >= nrows) return;
    int sub = lane >> 3;          // which of 8 edges in the group
    int q8  = (lane & 7) << 3;    // dim offset (8 bf16 = 16 B per lane)

    int beg = rowptr[wid];
    int end = rowptr[wid + 1];
    int len = end - beg;
    int nfull = len >> 3;

    float acc[8];
    #pragma unroll
    for (int k = 0; k < 8; ++k) acc[k] = 0.f;

    int e = beg + sub;
    #pragma unroll 8
    for (int g = 0; g < nfull; ++g, e += 8) {
        int2 cv = colval[e];
        float v = __int_as_float(cv.y);
        uint4 x = *reinterpret_cast<const uint4*>(xb + (size_t)cv.x * DIM + q8);
        acc[0] = fmaf(v, __uint_as_float(x.x << 16),          acc[0]);
        acc[1] = fmaf(v, __uint_as_float(x.x & 0xffff0000u),  acc[1]);
        acc[2] = fmaf(v, __uint_as_float(x.y << 16),          acc[2]);
        acc[3] = fmaf(v, __uint_as_float(x.y & 0xffff0000u),  acc[3]);
        acc[4] = fmaf(v, __uint_as_float(x.z << 16),          acc[4]);
        acc[5] = fmaf(v, __uint_as_float(x.z & 0xffff0000u),  acc[5]);
        acc[6] = fmaf(v, __uint_as_float(x.w << 16),          acc[6]);
        acc[7] = fmaf(v, __uint_as_float(x.w & 0xffff0000u),  acc[7]);
    }
    int rem = len & 7;
    if (sub < rem) {
        int2 cv = colval[e];
        float v = __int_as_float(cv.y);
        uint4 x = *reinterpret_cast<const uint4*>(xb + (size_t)cv.x * DIM + q8);
        acc[0] = fmaf(v, __uint_as_float(x.x << 16),          acc[0]);
        acc[1] = fmaf(v, __uint_as_float(x.x & 0xffff0000u),  acc[1]);
        acc[2] = fmaf(v, __uint_as_float(x.y << 16),          acc[2]);
        acc[3] = fmaf(v, __uint_as_float(x.y & 0xffff0000u),  acc[3]);
        acc[4] = fmaf(v, __uint_as_float(x.z << 16),          acc[4]);
        acc[5] = fmaf(v, __uint_as_float(x.z & 0xffff0000u),  acc[5]);
        acc[6] = fmaf(v, __uint_as_float(x.w << 16),          acc[6]);
        acc[7] = fmaf(v, __uint_as_float(x.w & 0xffff0000u),  acc[7]);
    }

    #pragma unroll
    for (int off = 8; off <= 32; off <<= 1) {
        #pragma unroll
        for (int k = 0; k < 8; ++k)
            acc[k] += __shfl_xor(acc[k], off);
    }

    if (sub == 0) {
        if (OUT16) {
            uint4 o;
            o.x = bf16_rne(acc[0]) | (bf16_rne(acc[1]) << 16);
            o.y = bf16_rne(acc[2]) | (bf16_rne(acc[3]) << 16);
            o.z = bf16_rne(acc[4]) | (bf16_rne(acc[5]) << 16);
            o.w = bf16_rne(acc[6]) | (bf16_rne(acc[7]) << 16);
            *reinterpret_cast<uint4*>(yb + (size_t)wid * DIM + q8) = o;
        } else {
            float* dst = yf + (size_t)wid * DIM + q8;
            *reinterpret_cast<float4*>(dst)     = make_float4(acc[0], acc[1], acc[2], acc[3]);
            *reinterpret_cast<float4*>(dst + 4) = make_float4(acc[4], acc[5], acc[6], acc[7]);
        }
    }
}

// ---------------- fallback: atomic scatter (round-1 path) ----------------
__global__ void spmm_atomic(const float* __restrict__ val,
                            const int* __restrict__ row,
                            const int* __restrict__ col,
                            const float* __restrict__ p0,
                            const float* __restrict__ p1,
                            int split,
                            float* __restrict__ y,
                            int nedges) {
    long long t = (long long)blockIdx.x * blockDim.x + threadIdx.x;
    int e = (int)(t >> 4);
    if (e >= nedges) return;
    int d = ((int)t & 15) << 2;
    float v = val[e];
    int r = row[e];
    int c = col[e];
    const float* src = (c < split) ? (p0 + (size_t)c * DIM)
                                   : (p1 + (size_t)(c - split) * DIM);
    float4 xv = *reinterpret_cast<const float4*>(src + d);
    float* o = y + (size_t)r * DIM + d;
    unsafeAtomicAdd(o + 0, v * xv.x);
    unsafeAtomicAdd(o + 1, v * xv.y);
    unsafeAtomicAdd(o + 2, v * xv.z);
    unsafeAtomicAdd(o + 3, v * xv.w);
}

extern "C" void kernel_launch(void* const* d_in, const int* in_sizes, int n_in,
                              void* d_out, int out_size, void* d_ws, size_t ws_size,
                              hipStream_t stream) {
    const float* user = (const float*)d_in[0];
    const float* item = (const float*)d_in[1];
    const float* val  = (const float*)d_in[2];
    const int*   row  = (const int*)d_in[3];
    const int*   col  = (const int*)d_in[4];

    int nU = in_sizes[0] / DIM;
    int nI = in_sizes[1] / DIM;
    int nE = in_sizes[2];
    int nN = nU + nI;
    int nb = (nN + BROWS - 1) >> BSH;
    int nblk = (nE + EPB - 1) / EPB;
    size_t bufElems = (size_t)nN * DIM;
    size_t n4 = bufElems / 4;

    // ---- workspace carve-up (256B aligned) ----
    char* base = (char*)d_ws;
    size_t off = 0;
    auto alloc = [&](size_t bytes) -> void* {
        void* p = base + off;
        off = (off + bytes + 255) & ~(size_t)255;
        return p;
    };
    size_t xBytes = bufElems * sizeof(float);                       // fallback ping
    size_t eBytes = (size_t)nE * sizeof(int2);                      // edges
    size_t bBytes = bufElems * 2 * sizeof(unsigned short);          // B0+B1 bf16
    size_t r0 = xBytes > eBytes ? xBytes : eBytes;
    if (bBytes > r0) r0 = bBytes;
    char*  region0 = (char*)alloc(r0);        // ebuf during build, then B0|B1 / fallback X
    int2*  colval  = (int2*)alloc(eBytes);    // row-sorted edges
    int*   rowptr  = (int*)alloc((size_t)(nN + 1) * sizeof(int));
    int*   runcnt  = (int*)alloc((size_t)nblk * nb * sizeof(int));
    int*   btotal  = (int*)alloc((size_t)nb * sizeof(int));
    int*   bstart  = (int*)alloc((size_t)(nb + 1) * sizeof(int));
    size_t needed  = off;

    float* Y = (float*)d_out;

    if (ws_size >= needed && nb <= MAXNB && nblk <= MAXNBLK && nN < (1 << 18)) {
        int2* ebuf = (int2*)region0;
        unsigned short* B0 = (unsigned short*)region0;
        unsigned short* B1 = B0 + bufElems;

        // ---- build row-sorted CSR ----
        count_chunks<<<nblk, 1024, 0, stream>>>(row, runcnt, nE, nb);
        scan_chunks<<<nb, 1024, 0, stream>>>(runcnt, btotal, nb, nblk);
        scan_buckets<<<1, 1024, 0, stream>>>(btotal, bstart, nb);
        scatter3<<<nblk, 1024, 0, stream>>>(row, col, val, bstart, runcnt, ebuf, nE, nb);
        local_sort<<<nb, 512, 0, stream>>>(ebuf, bstart, colval, rowptr, nN, nb);

        // ---- convert input embedding to bf16 (ebuf region now free) ----
        int cu = (nU * DIM) / 4, ci = (nI * DIM) / 4;
        f32_to_bf16<<<2048, 256, 0, stream>>>(user, B0, cu);
        f32_to_bf16<<<2048, 256, 0, stream>>>(item, B0 + (size_t)nU * DIM, ci);

        // ---- 4 propagation layers (bf16 gathers, fp32 accumulate) ----
        int sgrid = (int)(((size_t)nN * 64 + 255) / 256);
        spmm_bf16<true ><<<sgrid, 256, 0, stream>>>(colval, rowptr, B0, nullptr, B1, nN);
        spmm_bf16<true ><<<sgrid, 256, 0, stream>>>(colval, rowptr, B1, nullptr, B0, nN);
        spmm_bf16<true ><<<sgrid, 256, 0, stream>>>(colval, rowptr, B0, nullptr, B1, nN);
        spmm_bf16<false><<<sgrid, 256, 0, stream>>>(colval, rowptr, B1, Y, nullptr, nN);
    } else {
        // ---- fallback: atomic path (only needs X) ----
        float* X = (float*)region0;
        int zblocks = (int)((n4 + 255) / 256);
        if (zblocks > 4096) zblocks = 4096;
        long long totalThreads = (long long)nE * 16;
        dim3 sgrid((unsigned)((totalThreads + 255) / 256));
        const float* Xu = X;
        const float* Xi = X + (size_t)nU * DIM;
        const float* Yu = Y;
        const float* Yi = Y + (size_t)nU * DIM;
        zero_f4<<<zblocks, 256, 0, stream>>>(X, n4);
        spmm_atomic<<<sgrid, 256, 0, stream>>>(val, row, col, user, item, nU, X, nE);
        zero_f4<<<zblocks, 256, 0, stream>>>(Y, n4);
        spmm_atomic<<<sgrid, 256, 0, stream>>>(val, row, col, Xu, Xi, nU, Y, nE);
        zero_f4<<<zblocks, 256, 0, stream>>>(X, n4);
        spmm_atomic<<<sgrid, 256, 0, stream>>>(val, row, col, Yu, Yi, nU, X, nE);
        zero_f4<<<zblocks, 256, 0, stream>>>(Y, n4);
        spmm_atomic<<<sgrid, 256, 0, stream>>>(val, row, col, Xu, Xi, nU, Y, nE);
    }
}

// Round 15
// 442.560 us; speedup vs baseline: 1.7074x; 1.7074x over previous
//
#include <hip/hip_runtime.h>

#define DIM 64
#define BSH 8           // bucket shift: 256 rows per bucket
#define BROWS 256
#define MAXNB 1023      // max buckets (single-tile scans use 1024 threads)
#define EPB 4096        // edges per chunk (32KB LDS staging)
#define MAXNBLK 2048    // max chunks (ne <= 8.38M)

// ---------------- utility ----------------
__global__ void zero_f4(float* __restrict__ p, size_t n4) {
    size_t i = (size_t)blockIdx.x * blockDim.x + threadIdx.x;
    size_t stride = (size_t)gridDim.x * blockDim.x;
    float4 z = make_float4(0.f, 0.f, 0.f, 0.f);
    for (; i < n4; i += stride)
        reinterpret_cast<float4*>(p)[i] = z;
}

__device__ __forceinline__ unsigned int bf16_rne(float f) {
    unsigned int u = __float_as_uint(f);
    return (u + 0x7FFFu + ((u >> 16) & 1u)) >> 16;
}

// float -> bf16 (RNE), 4 elems/thread, grid-stride
__global__ void f32_to_bf16(const float* __restrict__ src,
                            unsigned short* __restrict__ dst, int n4) {
    int i = blockIdx.x * blockDim.x + threadIdx.x;
    int stride = gridDim.x * blockDim.x;
    for (; i < n4; i += stride) {
        float4 v = *reinterpret_cast<const float4*>(src + (size_t)i * 4);
        ushort4 o;
        o.x = (unsigned short)bf16_rne(v.x);
        o.y = (unsigned short)bf16_rne(v.y);
        o.z = (unsigned short)bf16_rne(v.z);
        o.w = (unsigned short)bf16_rne(v.w);
        *reinterpret_cast<ushort4*>(dst + (size_t)i * 4) = o;
    }
}

// ---------------- pass 1: per-chunk bucket histogram (vectorized reads) ----------------
__global__ __launch_bounds__(1024) void count_chunks(const int* __restrict__ row,
                                                     int* __restrict__ runcnt,
                                                     int ne, int nb) {
    __shared__ int h[1024];
    int blk = blockIdx.x, t = threadIdx.x;
    h[t] = 0;
    __syncthreads();
    int base = blk * EPB;
    int lim = base + EPB; if (lim > ne) lim = ne;
    if (lim - base == EPB) {
        int4 r4 = *reinterpret_cast<const int4*>(row + base + t * 4);
        atomicAdd(&h[r4.x >> BSH], 1);
        atomicAdd(&h[r4.y >> BSH], 1);
        atomicAdd(&h[r4.z >> BSH], 1);
        atomicAdd(&h[r4.w >> BSH], 1);
    } else {
        for (int e = base + t; e < lim; e += 1024)
            atomicAdd(&h[row[e] >> BSH], 1);
    }
    __syncthreads();
    if (t < nb) runcnt[(size_t)blk * nb + t] = h[t];
}

// ---------------- pass 2a: per-bucket exclusive scan across chunks (in place) ----------------
__global__ __launch_bounds__(1024) void scan_chunks(int* __restrict__ runcnt,
                                                    int* __restrict__ btotal,
                                                    int nb, int nblk) {
    __shared__ int sc[1024];
    __shared__ int carry;
    int b = blockIdx.x, t = threadIdx.x;
    if (t == 0) carry = 0;
    __syncthreads();
    for (int off = 0; off < nblk; off += 1024) {
        int i = off + t;
        int v = (i < nblk) ? runcnt[(size_t)i * nb + b] : 0;
        sc[t] = v;
        __syncthreads();
        for (int d = 1; d < 1024; d <<= 1) {
            int a = (t >= d) ? sc[t - d] : 0;
            __syncthreads();
            sc[t] += a;
            __syncthreads();
        }
        int excl = carry + sc[t] - v;
        if (i < nblk) runcnt[(size_t)i * nb + b] = excl;
        __syncthreads();
        if (t == 1023) carry += sc[1023];
        __syncthreads();
    }
    if (t == 0) btotal[b] = carry;
}

// ---------------- pass 2b: exclusive scan of bucket totals -> bstart ----------------
__global__ __launch_bounds__(1024) void scan_buckets(const int* __restrict__ btotal,
                                                     int* __restrict__ bstart, int nb) {
    __shared__ int sc[1024];
    int t = threadIdx.x;
    int v = (t < nb) ? btotal[t] : 0;
    sc[t] = v;
    __syncthreads();
    for (int d = 1; d < 1024; d <<= 1) {
        int a = (t >= d) ? sc[t - d] : 0;
        __syncthreads();
        sc[t] += a;
        __syncthreads();
    }
    if (t < nb) bstart[t] = sc[t] - v;
    if (t == 0) bstart[nb] = sc[1023];
}

// ---------------- pass 3: LDS-staged scatter with coalesced writeout ----------------
// Sorts the chunk by bucket in LDS, then writes each bucket-run with consecutive
// lanes -> consecutive addresses. packs {col | row_lo<<18, val}.
__global__ __launch_bounds__(1024) void scatter3(const int* __restrict__ row,
                                                 const int* __restrict__ col,
                                                 const float* __restrict__ val,
                                                 const int* __restrict__ bstart,
                                                 const int* __restrict__ runcnt,
                                                 int2* __restrict__ ebuf,
                                                 int ne, int nb) {
    __shared__ int2 data[EPB];            // 32 KB
    __shared__ unsigned short bkt[EPB];   // 8 KB
    __shared__ int cur[1024];             // hist -> local cursor
    __shared__ int gbase[1024];
    __shared__ int sc[1024];
    int blk = blockIdx.x, t = threadIdx.x;
    int base = blk * EPB;
    int lim = base + EPB; if (lim > ne) lim = ne;
    int len = lim - base;
    bool full = (len == EPB);

    cur[t] = 0;
    __syncthreads();
    if (full) {
        int4 r4 = *reinterpret_cast<const int4*>(row + base + t * 4);
        atomicAdd(&cur[r4.x >> BSH], 1);
        atomicAdd(&cur[r4.y >> BSH], 1);
        atomicAdd(&cur[r4.z >> BSH], 1);
        atomicAdd(&cur[r4.w >> BSH], 1);
    } else {
        for (int e = base + t; e < lim; e += 1024)
            atomicAdd(&cur[row[e] >> BSH], 1);
    }
    __syncthreads();

    int v = cur[t];
    sc[t] = v;
    __syncthreads();
    for (int d = 1; d < 1024; d <<= 1) {
        int a = (t >= d) ? sc[t - d] : 0;
        __syncthreads();
        sc[t] += a;
        __syncthreads();
    }
    int excl = sc[t] - v;
    if (t < nb) gbase[t] = bstart[t] + runcnt[(size_t)blk * nb + t] - excl;
    cur[t] = excl;
    __syncthreads();

    if (full) {
        int4   r4 = *reinterpret_cast<const int4*>(row + base + t * 4);
        int4   c4 = *reinterpret_cast<const int4*>(col + base + t * 4);
        float4 v4 = *reinterpret_cast<const float4*>(val + base + t * 4);
        int rr[4] = {r4.x, r4.y, r4.z, r4.w};
        int cc[4] = {c4.x, c4.y, c4.z, c4.w};
        float vv[4] = {v4.x, v4.y, v4.z, v4.w};
        #pragma unroll
        for (int k = 0; k < 4; ++k) {
            int b = rr[k] >> BSH;
            int pos = atomicAdd(&cur[b], 1);
            data[pos] = make_int2(cc[k] | ((rr[k] & (BROWS - 1)) << 18),
                                  __float_as_int(vv[k]));
            bkt[pos] = (unsigned short)b;
        }
    } else {
        for (int e = base + t; e < lim; e += 1024) {
            int r = row[e];
            int b = r >> BSH;
            int pos = atomicAdd(&cur[b], 1);
            data[pos] = make_int2(col[e] | ((r & (BROWS - 1)) << 18), __float_as_int(val[e]));
            bkt[pos] = (unsigned short)b;
        }
    }
    __syncthreads();

    for (int i = t; i < len; i += 1024) {
        int b = bkt[i];
        ebuf[gbase[b] + i] = data[i];
    }
}

// ---------------- pass 4: block per 256-row bucket, 256-bin row sort ----------------
__global__ __launch_bounds__(512) void local_sort(const int2* __restrict__ ein,
                                                  const int* __restrict__ bstart,
                                                  int2* __restrict__ eout,
                                                  int* __restrict__ rowptr,
                                                  int nrows, int nb) {
    __shared__ int hist[BROWS];
    __shared__ int cur[BROWS];
    __shared__ int wsum[4];
    int b = blockIdx.x;
    int t = threadIdx.x;
    int beg = bstart[b], end = bstart[b + 1];
    if (t < BROWS) hist[t] = 0;
    __syncthreads();
    for (int e = beg + t; e < end; e += 512)
        atomicAdd(&hist[((unsigned)ein[e].x) >> 18], 1);
    __syncthreads();
    int v = 0, s = 0;
    if (t < BROWS) {
        v = hist[t];
        s = v;
        #pragma unroll
        for (int off = 1; off < 64; off <<= 1) {
            int a = __shfl_up(s, off);
            if ((t & 63) >= off) s += a;
        }
        if ((t & 63) == 63) wsum[t >> 6] = s;
    }
    __syncthreads();
    if (t < BROWS) {
        int woff = 0;
        #pragma unroll
        for (int w = 0; w < 4; ++w)
            if (w < (t >> 6)) woff += wsum[w];
        int excl = woff + s - v;
        cur[t] = excl;
        int r = (b << BSH) + t;
        if (r < nrows) rowptr[r] = beg + excl;
    }
    if (b == nb - 1 && t == 0) rowptr[nrows] = end;
    __syncthreads();
    for (int e = beg + t; e < end; e += 512) {
        int2 cv = ein[e];
        int rl = ((unsigned)cv.x) >> 18;
        int pos = beg + atomicAdd(&cur[rl], 1);
        eout[pos] = make_int2(cv.x & 0x3FFFF, cv.y);
    }
}

// ---------------- bf16 CSR SpMM: one wave per row, 8 edges x 8 lanes x 16B ----------------
// Gathers bf16 rows (128 B), accumulates fp32, writes bf16 (OUT16) or fp32 (!OUT16).
// Plain int2 edge load; unroll 4 (32 VGPR, ~73% occupancy) — unroll 8 measured
// -2x (52 VGPR -> 39% occupancy; TLP is the latency hider here, not ILP).
template<bool OUT16>
__global__ __launch_bounds__(256) void spmm_bf16(const int2* __restrict__ colval,
                                                 const int* __restrict__ rowptr,
                                                 const unsigned short* __restrict__ xb,
                                                 float* __restrict__ yf,
                                                 unsigned short* __restrict__ yb,
                                                 int nrows) {
    int wid  = (int)(((size_t)blockIdx.x * blockDim.x + threadIdx.x) >> 6);
    int lane = threadIdx.x & 63;
    if (wid >= nrows) return;
    int sub = lane >> 3;          // which of 8 edges in the group
    int q8  = (lane & 7) << 3;    // dim offset (8 bf16 = 16 B per lane)

    int beg = rowptr[wid];
    int end = rowptr[wid + 1];
    int len = end - beg;
    int nfull = len >> 3;

    float acc[8];
    #pragma unroll
    for (int k = 0; k < 8; ++k) acc[k] = 0.f;

    int e = beg + sub;
    #pragma unroll 4
    for (int g = 0; g < nfull; ++g, e += 8) {
        int2 cv = colval[e];
        float v = __int_as_float(cv.y);
        uint4 x = *reinterpret_cast<const uint4*>(xb + (size_t)cv.x * DIM + q8);
        acc[0] = fmaf(v, __uint_as_float(x.x << 16),          acc[0]);
        acc[1] = fmaf(v, __uint_as_float(x.x & 0xffff0000u),  acc[1]);
        acc[2] = fmaf(v, __uint_as_float(x.y << 16),          acc[2]);
        acc[3] = fmaf(v, __uint_as_float(x.y & 0xffff0000u),  acc[3]);
        acc[4] = fmaf(v, __uint_as_float(x.z << 16),          acc[4]);
        acc[5] = fmaf(v, __uint_as_float(x.z & 0xffff0000u),  acc[5]);
        acc[6] = fmaf(v, __uint_as_float(x.w << 16),          acc[6]);
        acc[7] = fmaf(v, __uint_as_float(x.w & 0xffff0000u),  acc[7]);
    }
    int rem = len & 7;
    if (sub < rem) {
        int2 cv = colval[e];
        float v = __int_as_float(cv.y);
        uint4 x = *reinterpret_cast<const uint4*>(xb + (size_t)cv.x * DIM + q8);
        acc[0] = fmaf(v, __uint_as_float(x.x << 16),          acc[0]);
        acc[1] = fmaf(v, __uint_as_float(x.x & 0xffff0000u),  acc[1]);
        acc[2] = fmaf(v, __uint_as_float(x.y << 16),          acc[2]);
        acc[3] = fmaf(v, __uint_as_float(x.y & 0xffff0000u),  acc[3]);
        acc[4] = fmaf(v, __uint_as_float(x.z << 16),          acc[4]);
        acc[5] = fmaf(v, __uint_as_float(x.z & 0xffff0000u),  acc[5]);
        acc[6] = fmaf(v, __uint_as_float(x.w << 16),          acc[6]);
        acc[7] = fmaf(v, __uint_as_float(x.w & 0xffff0000u),  acc[7]);
    }

    #pragma unroll
    for (int off = 8; off <= 32; off <<= 1) {
        #pragma unroll
        for (int k = 0; k < 8; ++k)
            acc[k] += __shfl_xor(acc[k], off);
    }

    if (sub == 0) {
        if (OUT16) {
            uint4 o;
            o.x = bf16_rne(acc[0]) | (bf16_rne(acc[1]) << 16);
            o.y = bf16_rne(acc[2]) | (bf16_rne(acc[3]) << 16);
            o.z = bf16_rne(acc[4]) | (bf16_rne(acc[5]) << 16);
            o.w = bf16_rne(acc[6]) | (bf16_rne(acc[7]) << 16);
            *reinterpret_cast<uint4*>(yb + (size_t)wid * DIM + q8) = o;
        } else {
            float* dst = yf + (size_t)wid * DIM + q8;
            *reinterpret_cast<float4*>(dst)     = make_float4(acc[0], acc[1], acc[2], acc[3]);
            *reinterpret_cast<float4*>(dst + 4) = make_float4(acc[4], acc[5], acc[6], acc[7]);
        }
    }
}

// ---------------- fallback: atomic scatter (round-1 path) ----------------
__global__ void spmm_atomic(const float* __restrict__ val,
                            const int* __restrict__ row,
                            const int* __restrict__ col,
                            const float* __restrict__ p0,
                            const float* __restrict__ p1,
                            int split,
                            float* __restrict__ y,
                            int nedges) {
    long long t = (long long)blockIdx.x * blockDim.x + threadIdx.x;
    int e = (int)(t >> 4);
    if (e >= nedges) return;
    int d = ((int)t & 15) << 2;
    float v = val[e];
    int r = row[e];
    int c = col[e];
    const float* src = (c < split) ? (p0 + (size_t)c * DIM)
                                   : (p1 + (size_t)(c - split) * DIM);
    float4 xv = *reinterpret_cast<const float4*>(src + d);
    float* o = y + (size_t)r * DIM + d;
    unsafeAtomicAdd(o + 0, v * xv.x);
    unsafeAtomicAdd(o + 1, v * xv.y);
    unsafeAtomicAdd(o + 2, v * xv.z);
    unsafeAtomicAdd(o + 3, v * xv.w);
}

extern "C" void kernel_launch(void* const* d_in, const int* in_sizes, int n_in,
                              void* d_out, int out_size, void* d_ws, size_t ws_size,
                              hipStream_t stream) {
    const float* user = (const float*)d_in[0];
    const float* item = (const float*)d_in[1];
    const float* val  = (const float*)d_in[2];
    const int*   row  = (const int*)d_in[3];
    const int*   col  = (const int*)d_in[4];

    int nU = in_sizes[0] / DIM;
    int nI = in_sizes[1] / DIM;
    int nE = in_sizes[2];
    int nN = nU + nI;
    int nb = (nN + BROWS - 1) >> BSH;
    int nblk = (nE + EPB - 1) / EPB;
    size_t bufElems = (size_t)nN * DIM;
    size_t n4 = bufElems / 4;

    // ---- workspace carve-up (256B aligned) ----
    char* base = (char*)d_ws;
    size_t off = 0;
    auto alloc = [&](size_t bytes) -> void* {
        void* p = base + off;
        off = (off + bytes + 255) & ~(size_t)255;
        return p;
    };
    size_t xBytes = bufElems * sizeof(float);                       // fallback ping
    size_t eBytes = (size_t)nE * sizeof(int2);                      // edges
    size_t bBytes = bufElems * 2 * sizeof(unsigned short);          // B0+B1 bf16
    size_t r0 = xBytes > eBytes ? xBytes : eBytes;
    if (bBytes > r0) r0 = bBytes;
    char*  region0 = (char*)alloc(r0);        // ebuf during build, then B0|B1 / fallback X
    int2*  colval  = (int2*)alloc(eBytes);    // row-sorted edges
    int*   rowptr  = (int*)alloc((size_t)(nN + 1) * sizeof(int));
    int*   runcnt  = (int*)alloc((size_t)nblk * nb * sizeof(int));
    int*   btotal  = (int*)alloc((size_t)nb * sizeof(int));
    int*   bstart  = (int*)alloc((size_t)(nb + 1) * sizeof(int));
    size_t needed  = off;

    float* Y = (float*)d_out;

    if (ws_size >= needed && nb <= MAXNB && nblk <= MAXNBLK && nN < (1 << 18)) {
        int2* ebuf = (int2*)region0;
        unsigned short* B0 = (unsigned short*)region0;
        unsigned short* B1 = B0 + bufElems;

        // ---- build row-sorted CSR ----
        count_chunks<<<nblk, 1024, 0, stream>>>(row, runcnt, nE, nb);
        scan_chunks<<<nb, 1024, 0, stream>>>(runcnt, btotal, nb, nblk);
        scan_buckets<<<1, 1024, 0, stream>>>(btotal, bstart, nb);
        scatter3<<<nblk, 1024, 0, stream>>>(row, col, val, bstart, runcnt, ebuf, nE, nb);
        local_sort<<<nb, 512, 0, stream>>>(ebuf, bstart, colval, rowptr, nN, nb);

        // ---- convert input embedding to bf16 (ebuf region now free) ----
        int cu = (nU * DIM) / 4, ci = (nI * DIM) / 4;
        f32_to_bf16<<<2048, 256, 0, stream>>>(user, B0, cu);
        f32_to_bf16<<<2048, 256, 0, stream>>>(item, B0 + (size_t)nU * DIM, ci);

        // ---- 4 propagation layers (bf16 gathers, fp32 accumulate) ----
        int sgrid = (int)(((size_t)nN * 64 + 255) / 256);
        spmm_bf16<true ><<<sgrid, 256, 0, stream>>>(colval, rowptr, B0, nullptr, B1, nN);
        spmm_bf16<true ><<<sgrid, 256, 0, stream>>>(colval, rowptr, B1, nullptr, B0, nN);
        spmm_bf16<true ><<<sgrid, 256, 0, stream>>>(colval, rowptr, B0, nullptr, B1, nN);
        spmm_bf16<false><<<sgrid, 256, 0, stream>>>(colval, rowptr, B1, Y, nullptr, nN);
    } else {
        // ---- fallback: atomic path (only needs X) ----
        float* X = (float*)region0;
        int zblocks = (int)((n4 + 255) / 256);
        if (zblocks > 4096) zblocks = 4096;
        long long totalThreads = (long long)nE * 16;
        dim3 sgrid((unsigned)((totalThreads + 255) / 256));
        const float* Xu = X;
        const float* Xi = X + (size_t)nU * DIM;
        const float* Yu = Y;
        const float* Yi = Y + (size_t)nU * DIM;
        zero_f4<<<zblocks, 256, 0, stream>>>(X, n4);
        spmm_atomic<<<sgrid, 256, 0, stream>>>(val, row, col, user, item, nU, X, nE);
        zero_f4<<<zblocks, 256, 0, stream>>>(Y, n4);
        spmm_atomic<<<sgrid, 256, 0, stream>>>(val, row, col, Xu, Xi, nU, Y, nE);
        zero_f4<<<zblocks, 256, 0, stream>>>(X, n4);
        spmm_atomic<<<sgrid, 256, 0, stream>>>(val, row, col, Yu, Yi, nU, X, nE);
        zero_f4<<<zblocks, 256, 0, stream>>>(Y, n4);
        spmm_atomic<<<sgrid, 256, 0, stream>>>(val, row, col, Xu, Xi, nU, Y, nE);
    }
}